// Round 1
// baseline (227.966 us; speedup 1.0000x reference)
//
#include <hip/hip_runtime.h>

#define DD 512
#define MM 64
#define BB 16
#define NN 8192
#define KK 4
#define DP1 513

// d_ws layout: [0 .. M*B-1] inv_norm (1024 floats)
// d_out layout: [0 .. N*D-1] writes, [N*D] loss scalar

__global__ __launch_bounds__(256) void norm_kernel(
    const float* __restrict__ U, float* __restrict__ inv_norm,
    float* __restrict__ loss_slot)
{
    const int m = blockIdx.x;
    const int t = threadIdx.x;
    const float* Um = U + (long)m * DP1 * BB;
    // 8208 elements per expert; idx == t (mod 256), and 256 % 16 == 0 so every
    // element this thread touches belongs to column b = t % 16. Coalesced.
    float acc = 0.f;
    for (int idx = t; idx < DP1 * BB; idx += 256) {
        float v = Um[idx];
        acc += v * v;
    }
    __shared__ float s[256];
    s[t] = acc;
    __syncthreads();
    if (t < BB) {
        float tot = 0.f;
        #pragma unroll
        for (int j = 0; j < 16; ++j) tot += s[t + 16 * j];
        inv_norm[m * BB + t] = rsqrtf(tot);
    }
    if (m == 0 && t == 0) *loss_slot = 0.f;  // zero loss accumulator each call
}

__global__ __launch_bounds__(256) void dense_write_kernel(
    const float* __restrict__ h_sparse,   // N*K*B
    const int*   __restrict__ topk,       // N*K
    const float* __restrict__ U,          // M*DP1*B
    const float* __restrict__ inv_norm,   // M*B
    float* __restrict__ out)              // N*D writes + 1 loss
{
    const int n = blockIdx.x;
    const int t = threadIdx.x;

    __shared__ float hs[KK * BB];    // h folded with inv_norm
    __shared__ float ho[KK * BB];    // original h
    __shared__ float inv_s[KK * BB];
    __shared__ int   eidx[KK];
    __shared__ float w_s[DD];
    __shared__ float red[256];

    if (t < KK) eidx[t] = topk[n * KK + t];
    __syncthreads();
    if (t < KK * BB) {
        const int k = t / BB, b = t % BB;
        const float h  = h_sparse[(long)n * KK * BB + t];
        const float iv = inv_norm[eidx[k] * BB + b];
        ho[t]    = h;
        inv_s[t] = iv;
        hs[t]    = h * iv;
    }
    __syncthreads();

    // ---- Phase 1: writes[n,d] = sum_{k,b} U[e_k,d,b] * hs[k,b] ----
    #pragma unroll
    for (int dd = 0; dd < 2; ++dd) {
        const int d = t + dd * 256;
        float w = 0.f;
        #pragma unroll
        for (int k = 0; k < KK; ++k) {
            const float4* row = (const float4*)(U + ((long)eidx[k] * DP1 + d) * BB);
            #pragma unroll
            for (int q = 0; q < 4; ++q) {
                const float4 u4 = row[q];
                w += u4.x * hs[k * BB + 4 * q + 0];
                w += u4.y * hs[k * BB + 4 * q + 1];
                w += u4.z * hs[k * BB + 4 * q + 2];
                w += u4.w * hs[k * BB + 4 * q + 3];
            }
        }
        w_s[d] = w;
        out[(long)n * DD + d] = w;
    }
    __syncthreads();

    // ---- Phase 2: recon[k,b] = inv[k,b] * sum_d U[e_k,d,b] * w_s[d] ----
    // thread t: (k,b) pair = t & 63, d-chunk = t >> 6 (4 chunks x 128 d)
    {
        const int pair = t & 63;
        const int k = pair >> 4, b = pair & 15;
        const int c = t >> 6;
        const float* Ucol = U + (long)eidx[k] * DP1 * BB + b;
        float p = 0.f;
        #pragma unroll 8
        for (int d = c * 128; d < c * 128 + 128; ++d) {
            p += Ucol[(long)d * BB] * w_s[d];
        }
        red[t] = p;
    }
    __syncthreads();

    if (t < 64) {
        const float recon = (red[t] + red[t + 64] + red[t + 128] + red[t + 192]) * inv_s[t];
        const float diff  = recon - ho[t];
        float sq = diff * diff;
        #pragma unroll
        for (int off = 32; off > 0; off >>= 1) sq += __shfl_down(sq, off, 64);
        if (t == 0) {
            atomicAdd(out + (long)NN * DD, sq * (1.0f / ((float)NN * KK * BB)));
        }
    }
}

extern "C" void kernel_launch(void* const* d_in, const int* in_sizes, int n_in,
                              void* d_out, int out_size, void* d_ws, size_t ws_size,
                              hipStream_t stream) {
    const float* h_sparse = (const float*)d_in[0];
    const int*   topk     = (const int*)d_in[1];
    const float* U        = (const float*)d_in[2];
    float* out      = (float*)d_out;
    float* inv_norm = (float*)d_ws;

    hipLaunchKernelGGL(norm_kernel, dim3(MM), dim3(256), 0, stream,
                       U, inv_norm, out + (long)NN * DD);
    hipLaunchKernelGGL(dense_write_kernel, dim3(NN), dim3(256), 0, stream,
                       h_sparse, topk, U, inv_norm, out);
}

// Round 2
// 171.257 us; speedup vs baseline: 1.3311x; 1.3311x over previous
//
#include <hip/hip_runtime.h>

#define DD 512
#define MM 64
#define BB 16
#define NN 8192
#define KK 4
#define DP1 513
#define CAP 1024          // bucket capacity per expert (max load ~620)
#define GPE 8             // blocks per expert in pass A / pass C
#define PART_OFF 524288   // byte offset of bf16 partial buffer in ws
#define NPAIR (NN * KK)

typedef unsigned int uint;
typedef unsigned short ushort;

__device__ __forceinline__ ushort f2bf(float f) {
    uint u = __builtin_bit_cast(uint, f);
    uint r = (u + 0x7FFFu + ((u >> 16) & 1u)) >> 16;
    return (ushort)r;
}
__device__ __forceinline__ float bf2f_lo(uint packed) {   // low halfword
    return __builtin_bit_cast(float, packed << 16);
}
__device__ __forceinline__ float bf2f_hi(uint packed) {   // high halfword
    return __builtin_bit_cast(float, packed & 0xFFFF0000u);
}

// ---------------------------------------------------------------------------
// Fast path kernels (expert-centric)
// ---------------------------------------------------------------------------

// Counting sort of pairs by expert. ws: [0..63] counts, [64..64+64*CAP) buckets.
__global__ __launch_bounds__(256) void build_buckets(
    const int* __restrict__ topk, int* __restrict__ ws)
{
    int* cnt = ws;
    int* bkt = ws + 64;
    __shared__ int lc[MM], lb[MM];
    const int t = threadIdx.x;
    if (t < MM) lc[t] = 0;
    __syncthreads();
    const int p = blockIdx.x * 256 + t;     // pair id = n*K + k
    const int e = topk[p];
    const int my = atomicAdd(&lc[e], 1);
    __syncthreads();
    if (t < MM) lb[t] = atomicAdd(&cnt[t], lc[t]);
    __syncthreads();
    bkt[e * CAP + lb[e] + my] = p;
}

// Pass A: per-(expert,block-slice), compute bf16 partial writes.
__global__ __launch_bounds__(256) void pass_writes(
    const float* __restrict__ h_sparse,
    const float* __restrict__ U,
    void* __restrict__ ws)
{
    const int e = blockIdx.x / GPE;
    const int g = blockIdx.x % GPE;
    const int t = threadIdx.x;
    const int lane = t & 63;
    const int pg = t >> 6;
    const float* Ug = U + (long)e * DP1 * BB;

    __shared__ float red_s[256];
    __shared__ float inv_s[BB];
    __shared__ int ids_s[16];

    // in-kernel column norms: b = i % 16 is fixed per thread (256 % 16 == 0)
    float a = 0.f;
    for (int i = t; i < DP1 * BB; i += 256) { float v = Ug[i]; a += v * v; }
    red_s[t] = a;
    __syncthreads();
    for (int s = 128; s >= 16; s >>= 1) {
        if (t < s) red_s[t] += red_s[t + s];
        __syncthreads();
    }
    if (t < BB) inv_s[t] = rsqrtf(red_s[t]);

    const int* cnt = (const int*)ws;
    const int* bkt = cnt + 64;
    const int c  = cnt[e];
    const int lo = (c * g) / GPE;
    const int hi = (c * (g + 1)) / GPE;
    const int nt = (hi - lo + 15) >> 4;
    ushort* part = (ushort*)((char*)ws + PART_OFF);

    for (int tile = 0; tile < nt; ++tile) {
        __syncthreads();
        if (t < 16) {
            const int i = lo + tile * 16 + t;
            ids_s[t] = (i < hi) ? bkt[e * CAP + i] : 0;
        }
        __syncthreads();

        // load h rows for this wave's 4 pairs into registers (folded inv_norm)
        float hs[4][16];
        #pragma unroll
        for (int pp = 0; pp < 4; ++pp) {
            const int p = pg * 4 + pp;
            const bool ok = (lo + tile * 16 + p) < hi;
            const int id = ids_s[p];
            const float4* hp = (const float4*)(h_sparse + (long)id * BB);
            #pragma unroll
            for (int q = 0; q < 4; ++q) {
                float4 hv = ok ? hp[q] : make_float4(0.f, 0.f, 0.f, 0.f);
                hs[pp][4 * q + 0] = hv.x * inv_s[4 * q + 0];
                hs[pp][4 * q + 1] = hv.y * inv_s[4 * q + 1];
                hs[pp][4 * q + 2] = hv.z * inv_s[4 * q + 2];
                hs[pp][4 * q + 3] = hv.w * inv_s[4 * q + 3];
            }
        }

        float acc[4][8];
        #pragma unroll
        for (int pp = 0; pp < 4; ++pp)
            #pragma unroll
            for (int dd = 0; dd < 8; ++dd) acc[pp][dd] = 0.f;

        #pragma unroll
        for (int dd = 0; dd < 8; ++dd) {
            const int d = dd * 64 + lane;
            const float4* up = (const float4*)(Ug + (long)d * BB);
            #pragma unroll
            for (int q = 0; q < 4; ++q) {
                const float4 u = up[q];
                #pragma unroll
                for (int pp = 0; pp < 4; ++pp) {
                    acc[pp][dd] += u.x * hs[pp][4 * q + 0]
                                 + u.y * hs[pp][4 * q + 1]
                                 + u.z * hs[pp][4 * q + 2]
                                 + u.w * hs[pp][4 * q + 3];
                }
            }
        }

        #pragma unroll
        for (int pp = 0; pp < 4; ++pp) {
            const int p = pg * 4 + pp;
            if ((lo + tile * 16 + p) < hi) {
                const int id = ids_s[p];
                const int n = id >> 2, k = id & 3;
                ushort* prow = part + ((long)(k * NN + n) << 9);
                #pragma unroll
                for (int dd = 0; dd < 8; ++dd)
                    prow[dd * 64 + lane] = f2bf(acc[pp][dd]);
            }
        }
    }
}

// Pass B: writes[n,d] = sum_k partial[k][n][d]
__global__ __launch_bounds__(256) void pass_reduce(
    const void* __restrict__ ws, float* __restrict__ out)
{
    const uint4* part4 = (const uint4*)((const char*)ws + PART_OFF);
    const int gsz = NN * DD / 8;   // uint4 groups per k
    const int gid = blockIdx.x * 256 + threadIdx.x;
    float s[8];
    #pragma unroll
    for (int j = 0; j < 8; ++j) s[j] = 0.f;
    #pragma unroll
    for (int k = 0; k < KK; ++k) {
        const uint4 v = part4[(long)k * gsz + gid];
        s[0] += bf2f_lo(v.x); s[1] += bf2f_hi(v.x);
        s[2] += bf2f_lo(v.y); s[3] += bf2f_hi(v.y);
        s[4] += bf2f_lo(v.z); s[5] += bf2f_hi(v.z);
        s[6] += bf2f_lo(v.w); s[7] += bf2f_hi(v.w);
    }
    float4* out4 = (float4*)out;
    out4[(long)gid * 2 + 0] = make_float4(s[0], s[1], s[2], s[3]);
    out4[(long)gid * 2 + 1] = make_float4(s[4], s[5], s[6], s[7]);
}

// Pass C: recon + loss, expert-centric.
__global__ __launch_bounds__(256) void pass_recon(
    const float* __restrict__ h_sparse,
    const float* __restrict__ U,
    const void* __restrict__ ws,
    float* __restrict__ out)
{
    const int e = blockIdx.x / GPE;
    const int g = blockIdx.x % GPE;
    const int t = threadIdx.x;
    const int pg = t >> 6;          // wave id: pairs pg*4..pg*4+3
    const int bg = (t >> 4) & 3;    // b quad
    const int dg = t & 15;          // d slice
    const float* Ug = U + (long)e * DP1 * BB;

    __shared__ float w_s[16 * DD];  // 32 KB
    __shared__ float red_s[256];
    __shared__ float inv_s[BB];
    __shared__ int ids_s[16];
    __shared__ float loss_s;

    float a = 0.f;
    for (int i = t; i < DP1 * BB; i += 256) { float v = Ug[i]; a += v * v; }
    red_s[t] = a;
    __syncthreads();
    for (int s = 128; s >= 16; s >>= 1) {
        if (t < s) red_s[t] += red_s[t + s];
        __syncthreads();
    }
    if (t < BB) inv_s[t] = rsqrtf(red_s[t]);
    if (t == 0) loss_s = 0.f;

    const int* cnt = (const int*)ws;
    const int* bkt = cnt + 64;
    const int c  = cnt[e];
    const int lo = (c * g) / GPE;
    const int hi = (c * (g + 1)) / GPE;
    const int nt = (hi - lo + 15) >> 4;

    for (int tile = 0; tile < nt; ++tile) {
        __syncthreads();
        if (t < 16) {
            const int i = lo + tile * 16 + t;
            ids_s[t] = (i < hi) ? bkt[e * CAP + i] : 0;
        }
        __syncthreads();
        // stage 16 writes rows (float4 coalesced)
        {
            float4* w4 = (float4*)w_s;
            #pragma unroll
            for (int j = 0; j < 8; ++j) {
                const int f = t + j * 256;           // 2048 float4s
                const int row = f >> 7, col = f & 127;
                const int n = ids_s[row] >> 2;
                w4[f] = ((const float4*)(out + (long)n * DD))[col];
            }
        }
        __syncthreads();

        float acc[4][4];
        #pragma unroll
        for (int pp = 0; pp < 4; ++pp)
            #pragma unroll
            for (int x = 0; x < 4; ++x) acc[pp][x] = 0.f;

        #pragma unroll 8
        for (int j = 0; j < 32; ++j) {
            const int d = j * 16 + dg;
            const float4 u = ((const float4*)(Ug + (long)d * BB))[bg];
            #pragma unroll
            for (int pp = 0; pp < 4; ++pp) {
                const float w = w_s[(pg * 4 + pp) * DD + d];
                acc[pp][0] += w * u.x;
                acc[pp][1] += w * u.y;
                acc[pp][2] += w * u.z;
                acc[pp][3] += w * u.w;
            }
        }
        // butterfly-reduce over the 16 d-slices (low 4 lane bits)
        #pragma unroll
        for (int off = 1; off < 16; off <<= 1) {
            #pragma unroll
            for (int pp = 0; pp < 4; ++pp)
                #pragma unroll
                for (int x = 0; x < 4; ++x)
                    acc[pp][x] += __shfl_xor(acc[pp][x], off, 64);
        }
        if (dg == 0) {
            float lsum = 0.f;
            #pragma unroll
            for (int pp = 0; pp < 4; ++pp) {
                const int p = pg * 4 + pp;
                if ((lo + tile * 16 + p) < hi) {
                    const int id = ids_s[p];
                    #pragma unroll
                    for (int x = 0; x < 4; ++x) {
                        const int b = bg * 4 + x;
                        const float recon = acc[pp][x] * inv_s[b];
                        const float diff = recon - h_sparse[(long)id * BB + b];
                        lsum += diff * diff;
                    }
                }
            }
            atomicAdd(&loss_s, lsum);
        }
    }
    __syncthreads();
    if (t == 0 && loss_s != 0.f)
        atomicAdd(out + (long)NN * DD, loss_s * (1.0f / ((float)NN * KK * BB)));
    else if (t == 0 && nt == 0 && e == 0 && g == 0) {
        // no-op; loss slot zeroed by memset
    }
}

// ---------------------------------------------------------------------------
// Fallback path (round-1 proven kernels) — used when ws is too small
// ---------------------------------------------------------------------------

__global__ __launch_bounds__(256) void norm_kernel(
    const float* __restrict__ U, float* __restrict__ inv_norm,
    float* __restrict__ loss_slot)
{
    const int m = blockIdx.x;
    const int t = threadIdx.x;
    const float* Um = U + (long)m * DP1 * BB;
    float acc = 0.f;
    for (int idx = t; idx < DP1 * BB; idx += 256) {
        float v = Um[idx];
        acc += v * v;
    }
    __shared__ float s[256];
    s[t] = acc;
    __syncthreads();
    if (t < BB) {
        float tot = 0.f;
        #pragma unroll
        for (int j = 0; j < 16; ++j) tot += s[t + 16 * j];
        inv_norm[m * BB + t] = rsqrtf(tot);
    }
    if (m == 0 && t == 0) *loss_slot = 0.f;
}

__global__ __launch_bounds__(256) void dense_write_kernel(
    const float* __restrict__ h_sparse,
    const int*   __restrict__ topk,
    const float* __restrict__ U,
    const float* __restrict__ inv_norm,
    float* __restrict__ out)
{
    const int n = blockIdx.x;
    const int t = threadIdx.x;

    __shared__ float hs[KK * BB];
    __shared__ float ho[KK * BB];
    __shared__ float inv_s[KK * BB];
    __shared__ int   eidx[KK];
    __shared__ float w_s[DD];
    __shared__ float red[256];

    if (t < KK) eidx[t] = topk[n * KK + t];
    __syncthreads();
    if (t < KK * BB) {
        const int k = t / BB, b = t % BB;
        const float h  = h_sparse[(long)n * KK * BB + t];
        const float iv = inv_norm[eidx[k] * BB + b];
        ho[t]    = h;
        inv_s[t] = iv;
        hs[t]    = h * iv;
    }
    __syncthreads();

    #pragma unroll
    for (int dd = 0; dd < 2; ++dd) {
        const int d = t + dd * 256;
        float w = 0.f;
        #pragma unroll
        for (int k = 0; k < KK; ++k) {
            const float4* row = (const float4*)(U + ((long)eidx[k] * DP1 + d) * BB);
            #pragma unroll
            for (int q = 0; q < 4; ++q) {
                const float4 u4 = row[q];
                w += u4.x * hs[k * BB + 4 * q + 0];
                w += u4.y * hs[k * BB + 4 * q + 1];
                w += u4.z * hs[k * BB + 4 * q + 2];
                w += u4.w * hs[k * BB + 4 * q + 3];
            }
        }
        w_s[d] = w;
        out[(long)n * DD + d] = w;
    }
    __syncthreads();

    {
        const int pair = t & 63;
        const int k = pair >> 4, b = pair & 15;
        const int ch = t >> 6;
        const float* Ucol = U + (long)eidx[k] * DP1 * BB + b;
        float p = 0.f;
        #pragma unroll 8
        for (int d = ch * 128; d < ch * 128 + 128; ++d) {
            p += Ucol[(long)d * BB] * w_s[d];
        }
        red[t] = p;
    }
    __syncthreads();

    if (t < 64) {
        const float recon = (red[t] + red[t + 64] + red[t + 128] + red[t + 192]) * inv_s[t];
        const float diff  = recon - ho[t];
        float sq = diff * diff;
        #pragma unroll
        for (int off = 32; off > 0; off >>= 1) sq += __shfl_down(sq, off, 64);
        if (t == 0) {
            atomicAdd(out + (long)NN * DD, sq * (1.0f / ((float)NN * KK * BB)));
        }
    }
}

// ---------------------------------------------------------------------------

extern "C" void kernel_launch(void* const* d_in, const int* in_sizes, int n_in,
                              void* d_out, int out_size, void* d_ws, size_t ws_size,
                              hipStream_t stream) {
    const float* h_sparse = (const float*)d_in[0];
    const int*   topk     = (const int*)d_in[1];
    const float* U        = (const float*)d_in[2];
    float* out = (float*)d_out;

    const size_t need = (size_t)PART_OFF + (size_t)2 * KK * NN * DD; // 34,078,720 B

    if (ws_size >= need) {
        // zero expert counters + loss slot
        hipMemsetAsync(d_ws, 0, 64 * sizeof(int), stream);
        hipMemsetAsync((void*)(out + (long)NN * DD), 0, sizeof(float), stream);
        hipLaunchKernelGGL(build_buckets, dim3(NPAIR / 256), dim3(256), 0, stream,
                           topk, (int*)d_ws);
        hipLaunchKernelGGL(pass_writes, dim3(MM * GPE), dim3(256), 0, stream,
                           h_sparse, U, d_ws);
        hipLaunchKernelGGL(pass_reduce, dim3(NN * DD / 8 / 256), dim3(256), 0, stream,
                           d_ws, out);
        hipLaunchKernelGGL(pass_recon, dim3(MM * GPE), dim3(256), 0, stream,
                           h_sparse, U, d_ws, out);
    } else {
        float* inv_norm = (float*)d_ws;
        hipLaunchKernelGGL(norm_kernel, dim3(MM), dim3(256), 0, stream,
                           U, inv_norm, out + (long)NN * DD);
        hipLaunchKernelGGL(dense_write_kernel, dim3(NN), dim3(256), 0, stream,
                           h_sparse, topk, U, inv_norm, out);
    }
}